// Round 18
// baseline (96.594 us; speedup 1.0000x reference)
//
#include <hip/hip_runtime.h>

// LSTM (B=131072, T=24, input=3, H=32) + Linear(32,16)+ReLU+Linear(16,1)
//
// Composition of the three proven wins:
//   R8  : 2 batch streams/wave, all 32 MFMAs first, fused 8-chain ACT
//   R16 : whh frags in LDS (VGPR 44, occupancy 43%) — each ds_read_b128 frag
//         now feeds BOTH streams' MFMAs (halves LDS traffic per unit work)
//   R17 : sched_barrier(0) fences between ACT stages (latency buried by
//         cross-chain parallelism; o-gate MFMAs last, their exps after st.2)
// Unit->row permutation keeps h lane-local (no cross-lane traffic, no
// per-step barrier). Weights prescaled by log2e (2*log2e for g); c-state in
// 2*log2e domain so ez=exp2(cs). FP16 storage for h/w/x (R5 lesson).

typedef _Float16 f16x8 __attribute__((ext_vector_type(8)));
typedef _Float16 f16x4 __attribute__((ext_vector_type(4)));
typedef _Float16 f16x2 __attribute__((ext_vector_type(2)));
typedef float f32x4 __attribute__((ext_vector_type(4)));
typedef float f32x2 __attribute__((ext_vector_type(2)));

#define L2E 1.4426950408889634f
#define SBAR() __builtin_amdgcn_sched_barrier(0)

#if __has_builtin(__builtin_amdgcn_mfma_f32_16x16x16f16)
#define HAVE_MFMA16 1
#else
#define HAVE_MFMA16 0
#endif

__device__ __forceinline__ float fexp2(float v) { return __builtin_amdgcn_exp2f(v); }
__device__ __forceinline__ float frcp(float v)  { return __builtin_amdgcn_rcpf(v); }

__global__ __launch_bounds__(256, 4)
void lstm_fused(const float* __restrict__ x,
                const float* __restrict__ w_ih,
                const float* __restrict__ w_hh,
                const float* __restrict__ b_ih,
                const float* __restrict__ b_hh,
                const float* __restrict__ w1,
                const float* __restrict__ b1,
                const float* __restrict__ w2,
                const float* __restrict__ b2,
                float* __restrict__ out)
{
    __shared__ int2 xq[24 * 128];    // [t][n] packed f16 {x0,x1,x2,1.0} (24 KB)
    __shared__ int4 whhs[8 * 64];    // [frag m][c][g] f16x8 whh frags (8 KB)

    const int tid  = threadIdx.x;
    const int lane = tid & 63;
    const int wv   = tid >> 6;      // wave id 0..3
    const int c    = lane & 15;     // batch column within wave tile
    const int g    = lane >> 4;     // k-group 0..3
    const int blockBase = blockIdx.x * 128;

    // ---- stage x: pack (x0,x1,x2,1.0) as f16 per (row, t) ----
    for (int it = 0; it < 12; ++it) {
        int p = tid + it * 256;          // 0..3071 = 128 rows * 24 steps
        int n = p / 24;
        int t = p - n * 24;
        const float* xp = x + ((blockBase + n) * 24 + t) * 3;
        union { f16x4 h; int2 i2; } tq;
        tq.h[0] = (_Float16)xp[0];
        tq.h[1] = (_Float16)xp[1];
        tq.h[2] = (_Float16)xp[2];
        tq.h[3] = (_Float16)1.0f;        // hits fused-bias column
        xq[t * 128 + n] = tq.i2;
    }

    // ---- stage whh frags into LDS (lanes 0..63; all waves share) ----
    // MFMA (G,p) row r computes unit(r,p) = 8*(r>>2) + 4p + (r&3).
    // Frag element e = W[row=c][k = 8g+e], prescaled.
    const int ubase = 8 * (c >> 2) + (c & 3);
    if (tid < 64) {
#pragma unroll
        for (int G = 0; G < 4; ++G) {
            const float scale = (G == 2) ? (2.f * L2E) : L2E;
#pragma unroll
            for (int p = 0; p < 2; ++p) {
                const int row = G * 32 + ubase + 4 * p;
                const float* wr = w_hh + row * 32 + g * 8;
                union { f16x8 h; int4 i4; } a;
#pragma unroll
                for (int e = 0; e < 8; ++e) a.h[e] = (_Float16)(wr[e] * scale);
                whhs[(G * 2 + p) * 64 + c * 4 + g] = a.i4;
            }
        }
    }

    // ---- wib frags in registers (K=16 path) ----
#if HAVE_MFMA16
    f16x4 wib[8];
#else
    f16x8 wib[8];
#endif
#pragma unroll
    for (int G = 0; G < 4; ++G) {
        const float scale = (G == 2) ? (2.f * L2E) : L2E;
#pragma unroll
        for (int p = 0; p < 2; ++p) {
            const int row = G * 32 + ubase + 4 * p;
            _Float16 c0 = 0, c1 = 0, c2 = 0, c3 = 0;
            if (g == 0) {
                c0 = (_Float16)(w_ih[row * 3 + 0] * scale);
                c1 = (_Float16)(w_ih[row * 3 + 1] * scale);
                c2 = (_Float16)(w_ih[row * 3 + 2] * scale);
                c3 = (_Float16)((b_ih[row] + b_hh[row]) * scale);
            }
#if HAVE_MFMA16
            f16x4 bb = {c0, c1, c2, c3};
#else
            f16x8 bb = {c0, c1, c2, c3, 0, 0, 0, 0};
#endif
            wib[G * 2 + p] = bb;
        }
    }

    __syncthreads();   // xq/whhs staged (only barrier in the kernel)

    // ---- two independent batch streams per wave ----
    f32x2 cz = {0.f, 0.f};
    f32x2 cst2[8];                        // [s*4 + p*2 + j]
#pragma unroll
    for (int q = 0; q < 8; ++q) cst2[q] = cz;
    union hu_t { f16x2 p2[4]; f16x8 v; int4 i4; } hreg[2];
    hreg[0].i4 = make_int4(0, 0, 0, 0);
    hreg[1].i4 = make_int4(0, 0, 0, 0);

    const int n0 = wv * 16 + c;          // stream 0 column; stream 1: +64
    int2 xv[2];
    xv[0] = xq[n0];
    xv[1] = xq[n0 + 64];
    unsigned woff = (unsigned)(c * 4 + g);   // frag index within a frag row

#pragma unroll 1
    for (int t = 0; t < 24; ++t) {
        const int tn = (t < 23) ? t + 1 : 23;
        int2 xn0 = xq[tn * 128 + n0];        // prefetch next step
        int2 xn1 = xq[tn * 128 + n0 + 64];

        // opaque offset: stops ds_reads being hoisted/CSE'd out of the loop
        asm volatile("" : "+v"(woff));

        // ===== Phase A: all 32 MFMAs; each LDS frag feeds BOTH streams =====
        // gate order i,f,g first; o-gate (G=3) last — its exps issue late
        f32x4 acc[2][2][4];                  // [s][p][gate]
        const f32x4 z = {0.f, 0.f, 0.f, 0.f};
        f16x8 hfA = hreg[0].v;
        f16x8 hfB = hreg[1].v;
#pragma unroll
        for (int G = 0; G < 4; ++G)
#pragma unroll
            for (int p = 0; p < 2; ++p) {
                union { int4 i4; f16x8 h; } fr;
                fr.i4 = whhs[(2 * G + p) * 64 + woff];   // ds_read_b128
                acc[0][p][G] = __builtin_amdgcn_mfma_f32_16x16x32_f16(
                    fr.h, hfA, z, 0, 0, 0);
                acc[1][p][G] = __builtin_amdgcn_mfma_f32_16x16x32_f16(
                    fr.h, hfB, z, 0, 0, 0);
            }
#pragma unroll
        for (int s = 0; s < 2; ++s) {
            int xlo = (g == 0) ? xv[s].x : 0;
            int xhi = (g == 0) ? xv[s].y : 0;
#if HAVE_MFMA16
            union { int2 i2; f16x4 v; } xu;
            xu.i2 = make_int2(xlo, xhi);
            f16x4 xf = xu.v;
#else
            union { int4 i4; f16x8 v; } xu;
            xu.i4 = make_int4(xlo, xhi, 0, 0);
            f16x8 xf = xu.v;
#endif
#pragma unroll
            for (int G = 0; G < 4; ++G)
#pragma unroll
                for (int p = 0; p < 2; ++p)
#if HAVE_MFMA16
                    acc[s][p][G] = __builtin_amdgcn_mfma_f32_16x16x16f16(
                        wib[2 * G + p], xf, acc[s][p][G], 0, 0, 0);
#else
                    acc[s][p][G] = __builtin_amdgcn_mfma_f32_16x16x32_f16(
                        wib[2 * G + p], xf, acc[s][p][G], 0, 0, 0);
#endif
        }
        SBAR();

        // ===== Phase B: per-stream fenced stage-parallel ACT (4 chains) =====
        const f32x2 one = {1.f, 1.f};
        const f32x2 K2  = {2.f * L2E, 2.f * L2E};
#pragma unroll
        for (int s = 0; s < 2; ++s) {
            f32x2 ex[4], ey[4], ef[4];
#pragma unroll
            for (int q = 0; q < 4; ++q) {    // stage 1: i/g/f exps
                const int p = q >> 1, j = q & 1;
                ex[q][0] = fexp2(-acc[s][p][0][2 * j]); ex[q][1] = fexp2(-acc[s][p][0][2 * j + 1]);
                ey[q][0] = fexp2( acc[s][p][2][2 * j]); ey[q][1] = fexp2( acc[s][p][2][2 * j + 1]);
                ef[q][0] = fexp2(-acc[s][p][1][2 * j]); ef[q][1] = fexp2(-acc[s][p][1][2 * j + 1]);
            }
            SBAR();
            f32x2 axy[4], efp[4], r1[4];
#pragma unroll
            for (int q = 0; q < 4; ++q) {    // stage 2: denominators + rcp
                axy[q] = (one + ex[q]) * (one + ey[q]);
                efp[q] = one + ef[q];
                f32x2 dd = axy[q] * efp[q];
                r1[q][0] = frcp(dd[0]); r1[q][1] = frcp(dd[1]);
            }
            SBAR();
            f32x2 ew[4];
#pragma unroll
            for (int q = 0; q < 4; ++q) {    // sig(o) exps (o-MFMA long done)
                const int p = q >> 1, j = q & 1;
                ew[q][0] = fexp2(-acc[s][p][3][2 * j]);
                ew[q][1] = fexp2(-acc[s][p][3][2 * j + 1]);
            }
            SBAR();
            f32x2 ez[4];
#pragma unroll
            for (int q = 0; q < 4; ++q) {    // stage 3: c update + exp2
                f32x2 igs = (ey[q] * K2 - K2) * efp[q] * r1[q];
                f32x2 fs  = axy[q] * r1[q];
                cst2[s * 4 + q] = fs * cst2[s * 4 + q] + igs;
                ez[q][0] = fexp2(cst2[s * 4 + q][0]);
                ez[q][1] = fexp2(cst2[s * 4 + q][1]);
            }
            SBAR();
#pragma unroll
            for (int q = 0; q < 4; ++q) {    // stage 4: h = sig(o)*tanh(c)
                f32x2 d2 = (one + ew[q]) * (one + ez[q]);
                f32x2 r2; r2[0] = frcp(d2[0]); r2[1] = frcp(d2[1]);
                f32x2 hn = (ez[q] - one) * r2;
                f16x2 hh; hh[0] = (_Float16)hn[0]; hh[1] = (_Float16)hn[1];
                hreg[s].p2[q] = hh;
            }
            SBAR();
        }
        xv[0] = xn0;
        xv[1] = xn1;
    }

    // ---- head (one-time): read w1/b1/w2/b2 straight from global ----
#pragma unroll
    for (int s = 0; s < 2; ++s) {
        float hfin[8];
#pragma unroll
        for (int d = 0; d < 8; ++d) hfin[d] = (float)hreg[s].v[d];
        float hid[16];
#pragma unroll
        for (int q = 0; q < 16; ++q) {
            const float4* wrow = (const float4*)(w1 + q * 32 + g * 8);
            float4 wa = wrow[0], wb = wrow[1];
            float sm = wa.x * hfin[0] + wa.y * hfin[1] + wa.z * hfin[2] + wa.w * hfin[3]
                     + wb.x * hfin[4] + wb.y * hfin[5] + wb.z * hfin[6] + wb.w * hfin[7];
            sm += __shfl_xor(sm, 16);
            sm += __shfl_xor(sm, 32);
            hid[q] = sm;
        }
        float po = b2[0];
#pragma unroll
        for (int q = 0; q < 16; ++q)
            po = fmaf(fmaxf(hid[q] + b1[q], 0.f), w2[q], po);
        if (g == 0) out[blockBase + s * 64 + n0] = po;
    }
}

extern "C" void kernel_launch(void* const* d_in, const int* in_sizes, int n_in,
                              void* d_out, int out_size, void* d_ws, size_t ws_size,
                              hipStream_t stream) {
    (void)in_sizes; (void)n_in; (void)d_ws; (void)ws_size; (void)out_size;
    const float* x    = (const float*)d_in[0];
    const float* w_ih = (const float*)d_in[1];
    const float* w_hh = (const float*)d_in[2];
    const float* b_ih = (const float*)d_in[3];
    const float* b_hh = (const float*)d_in[4];
    const float* w1   = (const float*)d_in[5];
    const float* b1   = (const float*)d_in[6];
    const float* w2   = (const float*)d_in[7];
    const float* b2   = (const float*)d_in[8];
    float* outp = (float*)d_out;

    dim3 grid(131072 / 128);   // 128 rows per block (4 waves x 16 x 2 streams)
    dim3 block(256);
    hipLaunchKernelGGL(lstm_fused, grid, block, 0, stream,
                       x, w_ih, w_hh, b_ih, b_hh, w1, b1, w2, b2, outp);
}

// Round 22
// 94.857 us; speedup vs baseline: 1.0183x; 1.0183x over previous
//
#include <hip/hip_runtime.h>

// LSTM (B=131072, T=24, input=3, H=32) + Linear(32,16)+ReLU+Linear(16,1)
//
// R17 (best, 93.0us): whh frags in LDS (VGPR 44, occ 43%), 1 stream/wave,
// fenced stage-parallel ACT, plain-C f32x2 arithmetic (pk-asm abandoned:
// R20/R21 failed identically on this structure; R17's C path is proven).
// NEW: Phase A reordered — issue all 8 ds_read_b128 frags, run the 8
// register-only wib (x-path) MFMAs during the ~120cy LDS latency, then the
// 8 whh MFMAs accumulate. Hides the per-step LDS wait that previously
// stalled the first whh MFMA. Accumulation-order change only (same class
// as R7/R8 reorders that kept absmax at 9.77e-4).
// Unit->row permutation keeps h lane-local. Weights prescaled by log2e
// (2*log2e for g); c-state in 2*L2E domain. FP16 storage (R5 lesson).

typedef _Float16 f16x8 __attribute__((ext_vector_type(8)));
typedef _Float16 f16x4 __attribute__((ext_vector_type(4)));
typedef _Float16 f16x2 __attribute__((ext_vector_type(2)));
typedef float f32x4 __attribute__((ext_vector_type(4)));
typedef float f32x2 __attribute__((ext_vector_type(2)));

#define L2E 1.4426950408889634f
#define SBAR() __builtin_amdgcn_sched_barrier(0)

#if __has_builtin(__builtin_amdgcn_mfma_f32_16x16x16f16)
#define HAVE_MFMA16 1
#else
#define HAVE_MFMA16 0
#endif

__device__ __forceinline__ float fexp2(float v) { return __builtin_amdgcn_exp2f(v); }
__device__ __forceinline__ float frcp(float v)  { return __builtin_amdgcn_rcpf(v); }

__global__ __launch_bounds__(256, 5)
void lstm_fused(const float* __restrict__ x,
                const float* __restrict__ w_ih,
                const float* __restrict__ w_hh,
                const float* __restrict__ b_ih,
                const float* __restrict__ b_hh,
                const float* __restrict__ w1,
                const float* __restrict__ b1,
                const float* __restrict__ w2,
                const float* __restrict__ b2,
                float* __restrict__ out)
{
    __shared__ int2 xq[24 * 64];     // [t][n] packed f16 {x0,x1,x2,1.0} (12 KB)
    __shared__ int4 whhs[8 * 64];    // [frag m][c][g] f16x8 whh frags (8 KB)

    const int tid  = threadIdx.x;
    const int lane = tid & 63;
    const int wv   = tid >> 6;      // wave id 0..3
    const int c    = lane & 15;     // batch column within wave tile
    const int g    = lane >> 4;     // k-group 0..3
    const int blockBase = blockIdx.x * 64;

    // ---- stage x: pack (x0,x1,x2,1.0) as f16 per (row, t) ----
    for (int it = 0; it < 6; ++it) {
        int p = tid + it * 256;          // 0..1535 = 64 rows * 24 steps
        int n = p / 24;
        int t = p - n * 24;
        const float* xp = x + ((blockBase + n) * 24 + t) * 3;
        union { f16x4 h; int2 i2; } tq;
        tq.h[0] = (_Float16)xp[0];
        tq.h[1] = (_Float16)xp[1];
        tq.h[2] = (_Float16)xp[2];
        tq.h[3] = (_Float16)1.0f;        // hits fused-bias column
        xq[t * 64 + n] = tq.i2;
    }

    // ---- stage whh frags into LDS (lanes 0..63; all waves share) ----
    // MFMA (G,p) row r computes unit(r,p) = 8*(r>>2) + 4p + (r&3).
    // Frag element e = W[row=c][k = 8g+e], prescaled.
    const int ubase = 8 * (c >> 2) + (c & 3);
    if (tid < 64) {
#pragma unroll
        for (int G = 0; G < 4; ++G) {
            const float scale = (G == 2) ? (2.f * L2E) : L2E;
#pragma unroll
            for (int p = 0; p < 2; ++p) {
                const int row = G * 32 + ubase + 4 * p;
                const float* wr = w_hh + row * 32 + g * 8;
                union { f16x8 h; int4 i4; } a;
#pragma unroll
                for (int e = 0; e < 8; ++e) a.h[e] = (_Float16)(wr[e] * scale);
                whhs[(G * 2 + p) * 64 + c * 4 + g] = a.i4;
            }
        }
    }

    // ---- wib frags in registers (K=16 path) ----
#if HAVE_MFMA16
    f16x4 wib[8];
#else
    f16x8 wib[8];
#endif
#pragma unroll
    for (int G = 0; G < 4; ++G) {
        const float scale = (G == 2) ? (2.f * L2E) : L2E;
#pragma unroll
        for (int p = 0; p < 2; ++p) {
            const int row = G * 32 + ubase + 4 * p;
            _Float16 c0 = 0, c1 = 0, c2 = 0, c3 = 0;
            if (g == 0) {
                c0 = (_Float16)(w_ih[row * 3 + 0] * scale);
                c1 = (_Float16)(w_ih[row * 3 + 1] * scale);
                c2 = (_Float16)(w_ih[row * 3 + 2] * scale);
                c3 = (_Float16)((b_ih[row] + b_hh[row]) * scale);
            }
#if HAVE_MFMA16
            f16x4 bb = {c0, c1, c2, c3};
#else
            f16x8 bb = {c0, c1, c2, c3, 0, 0, 0, 0};
#endif
            wib[G * 2 + p] = bb;
        }
    }

    __syncthreads();   // xq/whhs staged (only barrier in the kernel)

    f32x2 cz = {0.f, 0.f};
    f32x2 cst2[4] = {cz, cz, cz, cz};    // [q = p*2 + j], 2*L2E-scaled c
    union hu_t { f16x2 p2[4]; f16x8 v; int4 i4; } hreg;
    hreg.i4 = make_int4(0, 0, 0, 0);

    const int n0 = wv * 16 + c;
    int2 xv = xq[n0];
    unsigned woff = (unsigned)(c * 4 + g);   // frag index within a frag row

#pragma unroll 1
    for (int t = 0; t < 24; ++t) {
        const int tn = (t < 23) ? t + 1 : 23;
        int2 xnxt = xq[tn * 64 + n0];        // prefetch next step

        // opaque offset: stops ds_reads being hoisted/CSE'd out of the loop
        asm volatile("" : "+v"(woff));

        // ================= Phase A =================
        // 1) issue all 8 whh-frag ds_reads (loads in flight)
        int4 fr[8];
#pragma unroll
        for (int m = 0; m < 8; ++m) fr[m] = whhs[m * 64 + woff];

        // 2) register-only wib (x-path) MFMAs execute during LDS latency
        f32x4 acc[2][4];                     // [p][gate]
        const f32x4 z = {0.f, 0.f, 0.f, 0.f};
        {
            int xlo = (g == 0) ? xv.x : 0;
            int xhi = (g == 0) ? xv.y : 0;
#if HAVE_MFMA16
            union { int2 i2; f16x4 v; } xu;
            xu.i2 = make_int2(xlo, xhi);
            f16x4 xf = xu.v;
#else
            union { int4 i4; f16x8 v; } xu;
            xu.i4 = make_int4(xlo, xhi, 0, 0);
            f16x8 xf = xu.v;
#endif
#pragma unroll
            for (int p = 0; p < 2; ++p)
#pragma unroll
                for (int G = 0; G < 4; ++G)
#if HAVE_MFMA16
                    acc[p][G] = __builtin_amdgcn_mfma_f32_16x16x16f16(
                        wib[2 * G + p], xf, z, 0, 0, 0);
#else
                    acc[p][G] = __builtin_amdgcn_mfma_f32_16x16x32_f16(
                        wib[2 * G + p], xf, z, 0, 0, 0);
#endif
        }

        // 3) whh MFMAs accumulate once frags arrive
        f16x8 hf = hreg.v;
#pragma unroll
        for (int p = 0; p < 2; ++p)
#pragma unroll
            for (int G = 0; G < 4; ++G) {
                union { int4 i4; f16x8 h; } u;
                u.i4 = fr[2 * G + p];
                acc[p][G] = __builtin_amdgcn_mfma_f32_16x16x32_f16(
                    u.h, hf, acc[p][G], 0, 0, 0);
            }

        // ====== Phase B: fenced stage-parallel ACT (R17, plain C) ======
        // q = p*2 + j ; pair j covers acc elements {2j, 2j+1}
        f32x2 ex[4], ey[4], ef[4];
#pragma unroll
        for (int q = 0; q < 4; ++q) {        // stage 1: i/g/f exps (12 trans)
            const int p = q >> 1, j = q & 1;
            ex[q][0] = fexp2(-acc[p][0][2 * j]); ex[q][1] = fexp2(-acc[p][0][2 * j + 1]);
            ey[q][0] = fexp2( acc[p][2][2 * j]); ey[q][1] = fexp2( acc[p][2][2 * j + 1]);
            ef[q][0] = fexp2(-acc[p][1][2 * j]); ef[q][1] = fexp2(-acc[p][1][2 * j + 1]);
        }
        SBAR();
        const f32x2 one = {1.f, 1.f};
        const f32x2 K2  = {2.f * L2E, 2.f * L2E};
        f32x2 axy[4], efp[4], r1[4];
#pragma unroll
        for (int q = 0; q < 4; ++q) {        // stage 2: denominators + rcp
            axy[q] = (one + ex[q]) * (one + ey[q]);
            efp[q] = one + ef[q];
            f32x2 dd = axy[q] * efp[q];
            r1[q][0] = frcp(dd[0]); r1[q][1] = frcp(dd[1]);
        }
        SBAR();
        f32x2 ew[4];
#pragma unroll
        for (int q = 0; q < 4; ++q) {        // sig(o) exps (o-MFMA long done)
            const int p = q >> 1, j = q & 1;
            ew[q][0] = fexp2(-acc[p][3][2 * j]);
            ew[q][1] = fexp2(-acc[p][3][2 * j + 1]);
        }
        SBAR();
        f32x2 ez[4];
#pragma unroll
        for (int q = 0; q < 4; ++q) {        // stage 3: c update + exp2
            f32x2 igs = (ey[q] * K2 - K2) * efp[q] * r1[q];
            f32x2 fs  = axy[q] * r1[q];
            cst2[q] = fs * cst2[q] + igs;
            ez[q][0] = fexp2(cst2[q][0]); ez[q][1] = fexp2(cst2[q][1]);
        }
        SBAR();
#pragma unroll
        for (int q = 0; q < 4; ++q) {        // stage 4: h = sig(o)*tanh(c)
            f32x2 d2 = (one + ew[q]) * (one + ez[q]);
            f32x2 r2; r2[0] = frcp(d2[0]); r2[1] = frcp(d2[1]);
            f32x2 hn = (ez[q] - one) * r2;
            f16x2 hh; hh[0] = (_Float16)hn[0]; hh[1] = (_Float16)hn[1];
            hreg.p2[q] = hh;
        }
        xv = xnxt;
    }

    // ---- head (one-time): read w1/b1/w2/b2 straight from global ----
    float hfin[8];
#pragma unroll
    for (int d = 0; d < 8; ++d) hfin[d] = (float)hreg.v[d];
    float hid[16];
#pragma unroll
    for (int q = 0; q < 16; ++q) {
        const float4* wrow = (const float4*)(w1 + q * 32 + g * 8);
        float4 wa = wrow[0], wb = wrow[1];
        float sm = wa.x * hfin[0] + wa.y * hfin[1] + wa.z * hfin[2] + wa.w * hfin[3]
                 + wb.x * hfin[4] + wb.y * hfin[5] + wb.z * hfin[6] + wb.w * hfin[7];
        sm += __shfl_xor(sm, 16);
        sm += __shfl_xor(sm, 32);
        hid[q] = sm;
    }
    float po = b2[0];
#pragma unroll
    for (int q = 0; q < 16; ++q)
        po = fmaf(fmaxf(hid[q] + b1[q], 0.f), w2[q], po);
    if (g == 0) out[blockBase + n0] = po;
}

extern "C" void kernel_launch(void* const* d_in, const int* in_sizes, int n_in,
                              void* d_out, int out_size, void* d_ws, size_t ws_size,
                              hipStream_t stream) {
    (void)in_sizes; (void)n_in; (void)d_ws; (void)ws_size; (void)out_size;
    const float* x    = (const float*)d_in[0];
    const float* w_ih = (const float*)d_in[1];
    const float* w_hh = (const float*)d_in[2];
    const float* b_ih = (const float*)d_in[3];
    const float* b_hh = (const float*)d_in[4];
    const float* w1   = (const float*)d_in[5];
    const float* b1   = (const float*)d_in[6];
    const float* w2   = (const float*)d_in[7];
    const float* b2   = (const float*)d_in[8];
    float* outp = (float*)d_out;

    dim3 grid(131072 / 64);    // 64 rows per block (4 waves x 16 x 1 stream)
    dim3 block(256);
    hipLaunchKernelGGL(lstm_fused, grid, block, 0, stream,
                       x, w_ih, w_hh, b_ih, b_hh, w1, b1, w2, b2, outp);
}

// Round 23
// 92.842 us; speedup vs baseline: 1.0404x; 1.0217x over previous
//
#include <hip/hip_runtime.h>

// LSTM (B=131072, T=24, input=3, H=32) + Linear(32,16)+ReLU+Linear(16,1)
//
// R17 (93.0us best) with the whhs LDS BANK-CONFLICT FIX: frag slot index
// changed from c*4+g to lane. Old layout made quarter-wave lanes read
// byte offsets 0,64,...,960 (banks {0,16} only -> 8-way conflict, 9.1e6
// SQ_LDS_BANK_CONFLICT, ~2.9x cost per b128 read, LDS BW shared by all
// waves on the CU). New layout: wave reads 1024 consecutive bytes, each
// 16-lane phase covers every bank exactly 2x (2-way aliasing = free).
// Slot index is a per-lane private bijection (same thread writes+reads),
// so this is a pure storage-order change — data identical.
// Everything else = R17: whh frags in LDS, 1 stream/wave, fenced
// stage-parallel ACT, plain-C f32x2 math, o-gate exps after stage 2.
// Weights prescaled by log2e (2*log2e for g); c-state in 2*L2E domain.

typedef _Float16 f16x8 __attribute__((ext_vector_type(8)));
typedef _Float16 f16x4 __attribute__((ext_vector_type(4)));
typedef _Float16 f16x2 __attribute__((ext_vector_type(2)));
typedef float f32x4 __attribute__((ext_vector_type(4)));
typedef float f32x2 __attribute__((ext_vector_type(2)));

#define L2E 1.4426950408889634f
#define SBAR() __builtin_amdgcn_sched_barrier(0)

#if __has_builtin(__builtin_amdgcn_mfma_f32_16x16x16f16)
#define HAVE_MFMA16 1
#else
#define HAVE_MFMA16 0
#endif

__device__ __forceinline__ float fexp2(float v) { return __builtin_amdgcn_exp2f(v); }
__device__ __forceinline__ float frcp(float v)  { return __builtin_amdgcn_rcpf(v); }

__global__ __launch_bounds__(256, 5)
void lstm_fused(const float* __restrict__ x,
                const float* __restrict__ w_ih,
                const float* __restrict__ w_hh,
                const float* __restrict__ b_ih,
                const float* __restrict__ b_hh,
                const float* __restrict__ w1,
                const float* __restrict__ b1,
                const float* __restrict__ w2,
                const float* __restrict__ b2,
                float* __restrict__ out)
{
    __shared__ int2 xq[24 * 64];     // [t][n] packed f16 {x0,x1,x2,1.0} (12 KB)
    __shared__ int4 whhs[8 * 64];    // [frag m][lane] f16x8 whh frags (8 KB)

    const int tid  = threadIdx.x;
    const int lane = tid & 63;
    const int wv   = tid >> 6;      // wave id 0..3
    const int c    = lane & 15;     // batch column within wave tile
    const int g    = lane >> 4;     // k-group 0..3
    const int blockBase = blockIdx.x * 64;

    // ---- stage x: pack (x0,x1,x2,1.0) as f16 per (row, t) ----
    for (int it = 0; it < 6; ++it) {
        int p = tid + it * 256;          // 0..1535 = 64 rows * 24 steps
        int n = p / 24;
        int t = p - n * 24;
        const float* xp = x + ((blockBase + n) * 24 + t) * 3;
        union { f16x4 h; int2 i2; } tq;
        tq.h[0] = (_Float16)xp[0];
        tq.h[1] = (_Float16)xp[1];
        tq.h[2] = (_Float16)xp[2];
        tq.h[3] = (_Float16)1.0f;        // hits fused-bias column
        xq[t * 64 + n] = tq.i2;
    }

    // ---- stage whh frags into LDS (lanes 0..63; all waves share) ----
    // MFMA (G,p) row r computes unit(r,p) = 8*(r>>2) + 4p + (r&3).
    // Frag element e = W[row=c][k = 8g+e], prescaled. Slot = lane (linear:
    // wave reads consecutive 16B/lane -> 2-way bank aliasing = free).
    const int ubase = 8 * (c >> 2) + (c & 3);
    if (tid < 64) {
#pragma unroll
        for (int G = 0; G < 4; ++G) {
            const float scale = (G == 2) ? (2.f * L2E) : L2E;
#pragma unroll
            for (int p = 0; p < 2; ++p) {
                const int row = G * 32 + ubase + 4 * p;
                const float* wr = w_hh + row * 32 + g * 8;
                union { f16x8 h; int4 i4; } a;
#pragma unroll
                for (int e = 0; e < 8; ++e) a.h[e] = (_Float16)(wr[e] * scale);
                whhs[(G * 2 + p) * 64 + lane] = a.i4;
            }
        }
    }

    // ---- wib frags in registers (K=16 path) ----
#if HAVE_MFMA16
    f16x4 wib[8];
#else
    f16x8 wib[8];
#endif
#pragma unroll
    for (int G = 0; G < 4; ++G) {
        const float scale = (G == 2) ? (2.f * L2E) : L2E;
#pragma unroll
        for (int p = 0; p < 2; ++p) {
            const int row = G * 32 + ubase + 4 * p;
            _Float16 c0 = 0, c1 = 0, c2 = 0, c3 = 0;
            if (g == 0) {
                c0 = (_Float16)(w_ih[row * 3 + 0] * scale);
                c1 = (_Float16)(w_ih[row * 3 + 1] * scale);
                c2 = (_Float16)(w_ih[row * 3 + 2] * scale);
                c3 = (_Float16)((b_ih[row] + b_hh[row]) * scale);
            }
#if HAVE_MFMA16
            f16x4 bb = {c0, c1, c2, c3};
#else
            f16x8 bb = {c0, c1, c2, c3, 0, 0, 0, 0};
#endif
            wib[G * 2 + p] = bb;
        }
    }

    __syncthreads();   // xq/whhs staged (only barrier in the kernel)

    f32x2 cz = {0.f, 0.f};
    f32x2 cst2[4] = {cz, cz, cz, cz};    // [q = p*2 + j], 2*L2E-scaled c
    union hu_t { f16x2 p2[4]; f16x8 v; int4 i4; } hreg;
    hreg.i4 = make_int4(0, 0, 0, 0);

    const int n0 = wv * 16 + c;
    int2 xv = xq[n0];
    unsigned woff = (unsigned)lane;      // linear slot: conflict-free b128

#pragma unroll 1
    for (int t = 0; t < 24; ++t) {
        const int tn = (t < 23) ? t + 1 : 23;
        int2 xnxt = xq[tn * 64 + n0];        // prefetch next step

        // opaque offset: stops ds_reads being hoisted/CSE'd out of the loop
        asm volatile("" : "+v"(woff));

        // ================= Phase A: all 16 MFMAs =================
        // gate order i,f,g first; o-gate last (its consumer ew issues late)
        f32x4 acc[2][4];                     // [p][gate]
        const f32x4 z = {0.f, 0.f, 0.f, 0.f};
        f16x8 hf = hreg.v;
#pragma unroll
        for (int p = 0; p < 2; ++p)
#pragma unroll
            for (int G = 0; G < 4; ++G) {
                union { int4 i4; f16x8 h; } fr;
                fr.i4 = whhs[(2 * G + p) * 64 + woff];   // ds_read_b128
                acc[p][G] = __builtin_amdgcn_mfma_f32_16x16x32_f16(
                    fr.h, hf, z, 0, 0, 0);
            }
        {
            int xlo = (g == 0) ? xv.x : 0;
            int xhi = (g == 0) ? xv.y : 0;
#if HAVE_MFMA16
            union { int2 i2; f16x4 v; } xu;
            xu.i2 = make_int2(xlo, xhi);
            f16x4 xf = xu.v;
#else
            union { int4 i4; f16x8 v; } xu;
            xu.i4 = make_int4(xlo, xhi, 0, 0);
            f16x8 xf = xu.v;
#endif
#pragma unroll
            for (int p = 0; p < 2; ++p)
#pragma unroll
                for (int G = 0; G < 4; ++G)
#if HAVE_MFMA16
                    acc[p][G] = __builtin_amdgcn_mfma_f32_16x16x16f16(
                        wib[2 * G + p], xf, acc[p][G], 0, 0, 0);
#else
                    acc[p][G] = __builtin_amdgcn_mfma_f32_16x16x32_f16(
                        wib[2 * G + p], xf, acc[p][G], 0, 0, 0);
#endif
        }

        // ====== Phase B: fenced stage-parallel ACT (R17, plain C) ======
        // q = p*2 + j ; pair j covers acc elements {2j, 2j+1}
        f32x2 ex[4], ey[4], ef[4];
#pragma unroll
        for (int q = 0; q < 4; ++q) {        // stage 1: i/g/f exps (12 trans)
            const int p = q >> 1, j = q & 1;
            ex[q][0] = fexp2(-acc[p][0][2 * j]); ex[q][1] = fexp2(-acc[p][0][2 * j + 1]);
            ey[q][0] = fexp2( acc[p][2][2 * j]); ey[q][1] = fexp2( acc[p][2][2 * j + 1]);
            ef[q][0] = fexp2(-acc[p][1][2 * j]); ef[q][1] = fexp2(-acc[p][1][2 * j + 1]);
        }
        SBAR();
        const f32x2 one = {1.f, 1.f};
        const f32x2 K2  = {2.f * L2E, 2.f * L2E};
        f32x2 axy[4], efp[4], r1[4];
#pragma unroll
        for (int q = 0; q < 4; ++q) {        // stage 2: denominators + rcp
            axy[q] = (one + ex[q]) * (one + ey[q]);
            efp[q] = one + ef[q];
            f32x2 dd = axy[q] * efp[q];
            r1[q][0] = frcp(dd[0]); r1[q][1] = frcp(dd[1]);
        }
        SBAR();
        f32x2 ew[4];
#pragma unroll
        for (int q = 0; q < 4; ++q) {        // sig(o) exps (o-MFMA long done)
            const int p = q >> 1, j = q & 1;
            ew[q][0] = fexp2(-acc[p][3][2 * j]);
            ew[q][1] = fexp2(-acc[p][3][2 * j + 1]);
        }
        SBAR();
        f32x2 ez[4];
#pragma unroll
        for (int q = 0; q < 4; ++q) {        // stage 3: c update + exp2
            f32x2 igs = (ey[q] * K2 - K2) * efp[q] * r1[q];
            f32x2 fs  = axy[q] * r1[q];
            cst2[q] = fs * cst2[q] + igs;
            ez[q][0] = fexp2(cst2[q][0]); ez[q][1] = fexp2(cst2[q][1]);
        }
        SBAR();
#pragma unroll
        for (int q = 0; q < 4; ++q) {        // stage 4: h = sig(o)*tanh(c)
            f32x2 d2 = (one + ew[q]) * (one + ez[q]);
            f32x2 r2; r2[0] = frcp(d2[0]); r2[1] = frcp(d2[1]);
            f32x2 hn = (ez[q] - one) * r2;
            f16x2 hh; hh[0] = (_Float16)hn[0]; hh[1] = (_Float16)hn[1];
            hreg.p2[q] = hh;
        }
        xv = xnxt;
    }

    // ---- head (one-time): read w1/b1/w2/b2 straight from global ----
    float hfin[8];
#pragma unroll
    for (int d = 0; d < 8; ++d) hfin[d] = (float)hreg.v[d];
    float hid[16];
#pragma unroll
    for (int q = 0; q < 16; ++q) {
        const float4* wrow = (const float4*)(w1 + q * 32 + g * 8);
        float4 wa = wrow[0], wb = wrow[1];
        float sm = wa.x * hfin[0] + wa.y * hfin[1] + wa.z * hfin[2] + wa.w * hfin[3]
                 + wb.x * hfin[4] + wb.y * hfin[5] + wb.z * hfin[6] + wb.w * hfin[7];
        sm += __shfl_xor(sm, 16);
        sm += __shfl_xor(sm, 32);
        hid[q] = sm;
    }
    float po = b2[0];
#pragma unroll
    for (int q = 0; q < 16; ++q)
        po = fmaf(fmaxf(hid[q] + b1[q], 0.f), w2[q], po);
    if (g == 0) out[blockBase + n0] = po;
}

extern "C" void kernel_launch(void* const* d_in, const int* in_sizes, int n_in,
                              void* d_out, int out_size, void* d_ws, size_t ws_size,
                              hipStream_t stream) {
    (void)in_sizes; (void)n_in; (void)d_ws; (void)ws_size; (void)out_size;
    const float* x    = (const float*)d_in[0];
    const float* w_ih = (const float*)d_in[1];
    const float* w_hh = (const float*)d_in[2];
    const float* b_ih = (const float*)d_in[3];
    const float* b_hh = (const float*)d_in[4];
    const float* w1   = (const float*)d_in[5];
    const float* b1   = (const float*)d_in[6];
    const float* w2   = (const float*)d_in[7];
    const float* b2   = (const float*)d_in[8];
    float* outp = (float*)d_out;

    dim3 grid(131072 / 64);    // 64 rows per block (4 waves x 16 x 1 stream)
    dim3 block(256);
    hipLaunchKernelGGL(lstm_fused, grid, block, 0, stream,
                       x, w_ih, w_hh, b_ih, b_hh, w1, b1, w2, b2, outp);
}